// Round 1
// baseline (4427.890 us; speedup 1.0000x reference)
//
#include <hip/hip_runtime.h>

#define BM 64
#define BN 64
#define BK 16

// ---------------- fp32 tiled GEMM: C[m, coff+n] = op(A) @ B (+bias) (relu) ----
// A: [M,K] row-major. B: [K,Nn] row-major. C row stride ldc.
template<bool RELU_IN, bool BIAS, bool RELU_OUT>
__global__ __launch_bounds__(256)
void gemm_f32(const float* __restrict__ A, const float* __restrict__ B,
              const float* __restrict__ bias, float* __restrict__ C,
              int M, int K, int Nn, int ldc, int coff)
{
    __shared__ float As[BK][BM + 4];   // +4 pad: keeps 16B alignment, breaks stride
    __shared__ float Bs[BK][BN];

    const int tid = threadIdx.x;       // 256 threads
    const int tx = tid & 15;           // N direction
    const int ty = tid >> 4;           // M direction
    const int mBase = blockIdx.x * BM;
    const int nBase = blockIdx.y * BN;

    float acc[4][4];
#pragma unroll
    for (int i = 0; i < 4; ++i)
#pragma unroll
        for (int j = 0; j < 4; ++j) acc[i][j] = 0.f;

    const int ar = tid >> 2;           // 0..63   (A tile row)
    const int ac = (tid & 3) * 4;      // 0,4,8,12 (A tile col, float4)
    const int br = tid >> 4;           // 0..15   (B tile row)
    const int bc = (tid & 15) * 4;     // 0..60   (B tile col, float4)

    for (int k0 = 0; k0 < K; k0 += BK) {
        float4 a4 = make_float4(0.f, 0.f, 0.f, 0.f);
        const int gm = mBase + ar;
        if (gm < M) a4 = *(const float4*)&A[(long long)gm * K + k0 + ac];
        if (RELU_IN) {
            a4.x = fmaxf(a4.x, 0.f); a4.y = fmaxf(a4.y, 0.f);
            a4.z = fmaxf(a4.z, 0.f); a4.w = fmaxf(a4.w, 0.f);
        }
        As[ac + 0][ar] = a4.x;
        As[ac + 1][ar] = a4.y;
        As[ac + 2][ar] = a4.z;
        As[ac + 3][ar] = a4.w;

        float4 b4 = *(const float4*)&B[(long long)(k0 + br) * Nn + nBase + bc];
        *(float4*)&Bs[br][bc] = b4;

        __syncthreads();
#pragma unroll
        for (int k = 0; k < BK; ++k) {
            float4 av = *(const float4*)&As[k][ty * 4];
            float4 bv = *(const float4*)&Bs[k][tx * 4];
            float a[4] = {av.x, av.y, av.z, av.w};
            float b[4] = {bv.x, bv.y, bv.z, bv.w};
#pragma unroll
            for (int i = 0; i < 4; ++i)
#pragma unroll
                for (int j = 0; j < 4; ++j)
                    acc[i][j] = fmaf(a[i], b[j], acc[i][j]);
        }
        __syncthreads();
    }

#pragma unroll
    for (int i = 0; i < 4; ++i) {
        const int gm = mBase + ty * 4 + i;
        if (gm >= M) continue;
        float4 o;
        float* op = &o.x;
#pragma unroll
        for (int j = 0; j < 4; ++j) {
            float v = acc[i][j];
            if (BIAS) v += bias[nBase + tx * 4 + j];
            if (RELU_OUT) v = fmaxf(v, 0.f);
            op[j] = v;
        }
        *(float4*)&C[(long long)gm * ldc + coff + nBase + tx * 4] = o;
    }
}

// ---------------- SpMM: out[dst, coff + :F] += w * x[src, :F] -----------------
// (1<<LOGF4) lanes per edge, each lane handles one float4.
template<int LOGF4>
__global__ __launch_bounds__(256)
void spmm_atomic(const float* __restrict__ x, const int* __restrict__ src,
                 const int* __restrict__ dst, const float* __restrict__ w,
                 float* __restrict__ out, int E, int ldx, int ldo, int coff)
{
    const long long idx = (long long)blockIdx.x * blockDim.x + threadIdx.x;
    const int e = (int)(idx >> LOGF4);
    const int f4 = (int)(idx & ((1 << LOGF4) - 1));
    if (e >= E) return;
    const int s = src[e];
    const int d = dst[e];
    const float wt = w[e];
    float4 v = *(const float4*)&x[(long long)s * ldx + f4 * 4];
    float* o = &out[(long long)d * ldo + coff + f4 * 4];
    unsafeAtomicAdd(o + 0, v.x * wt);
    unsafeAtomicAdd(o + 1, v.y * wt);
    unsafeAtomicAdd(o + 2, v.z * wt);
    unsafeAtomicAdd(o + 3, v.w * wt);
}

// ---------------- small helpers ----------------------------------------------
__global__ __launch_bounds__(256)
void zero4(float4* __restrict__ p, int n4)
{
    int i = blockIdx.x * blockDim.x + threadIdx.x;
    if (i < n4) p[i] = make_float4(0.f, 0.f, 0.f, 0.f);
}

__global__ __launch_bounds__(256)
void zero_slice(float* __restrict__ out, int N, int ldo, int coff, int w4)
{
    int i = blockIdx.x * blockDim.x + threadIdx.x;
    int row = i / w4, c = i % w4;
    if (row < N)
        *(float4*)&out[(long long)row * ldo + coff + c * 4] =
            make_float4(0.f, 0.f, 0.f, 0.f);
}

__global__ __launch_bounds__(256)
void relu_copy_slice(const float* __restrict__ in, float* __restrict__ out,
                     int N, int F, int ldo, int coff)
{
    int w4 = F / 4;
    int i = blockIdx.x * blockDim.x + threadIdx.x;
    int row = i / w4, c = i % w4;
    if (row >= N) return;
    float4 v = *(const float4*)&in[(long long)row * F + c * 4];
    v.x = fmaxf(v.x, 0.f); v.y = fmaxf(v.y, 0.f);
    v.z = fmaxf(v.z, 0.f); v.w = fmaxf(v.w, 0.f);
    *(float4*)&out[(long long)row * ldo + coff + c * 4] = v;
}

// ---------------- launch ------------------------------------------------------
extern "C" void kernel_launch(void* const* d_in, const int* in_sizes, int n_in,
                              void* d_out, int out_size, void* d_ws, size_t ws_size,
                              hipStream_t stream)
{
    const float* X    = (const float*)d_in[0];
    const int*   esrc = (const int*)  d_in[1];
    const int*   edst = (const int*)  d_in[2];
    const float* ew   = (const float*)d_in[3];
    const float* W1   = (const float*)d_in[4];
    const float* W2   = (const float*)d_in[5];
    const float* mw1  = (const float*)d_in[6];
    const float* mb1  = (const float*)d_in[7];
    const float* mw2  = (const float*)d_in[8];
    const float* mb2  = (const float*)d_in[9];

    const int IN_F = 256, HID_F = 256, OUT_F = 128;
    const int N  = in_sizes[0] / IN_F;
    const int E  = in_sizes[1];
    const int LD = OUT_F + HID_F + OUT_F;   // 512

    float* out  = (float*)d_out;
    float* bufA = (float*)d_ws;                       // Y1 [N,256], later g [N,128]
    float* bufB = bufA + (size_t)N * HID_F;           // S1 [N,256], later AX1 acc

    dim3 blk(256);
    const int mTiles = (N + BM - 1) / BM;

    // K1: S1 = relu(X @ mlp_w1 + b1)  -> bufB
    gemm_f32<false, true, true><<<dim3(mTiles, HID_F / BN), blk, 0, stream>>>(
        X, mw1, mb1, bufB, N, IN_F, HID_F, HID_F, 0);

    // K2: self_out = S1 @ mlp_w2 + b2 -> out[:, 0:128]
    gemm_f32<false, true, false><<<dim3(mTiles, OUT_F / BN), blk, 0, stream>>>(
        bufB, mw2, mb2, out, N, HID_F, OUT_F, LD, 0);

    // K3: Y1 = X @ W1 -> bufA   (A@(X@W1) == (A@X)@W1)
    gemm_f32<false, false, false><<<dim3(mTiles, HID_F / BN), blk, 0, stream>>>(
        X, W1, nullptr, bufA, N, IN_F, HID_F, HID_F, 0);

    // zero the SpMM1 accumulator (bufB, reused) and the h2 output slice
    {
        int n4 = N * HID_F / 4;
        zero4<<<(n4 + 255) / 256, blk, 0, stream>>>((float4*)bufB, n4);
        int ns = N * (OUT_F / 4);
        zero_slice<<<(ns + 255) / 256, blk, 0, stream>>>(out, N, LD, OUT_F + HID_F, OUT_F / 4);
    }

    // SpMM1: bufB[dst] += w * Y1[src]   (F=256 -> 64 lanes/edge)
    {
        long long tot = (long long)E * (HID_F / 4);
        spmm_atomic<6><<<(int)((tot + 255) / 256), blk, 0, stream>>>(
            bufA, esrc, edst, ew, bufB, E, HID_F, HID_F, 0);
    }

    // h1 = relu(bufB) -> out[:, 128:384]
    relu_copy_slice<<<(N * (HID_F / 4) + 255) / 256, blk, 0, stream>>>(
        bufB, out, N, HID_F, LD, OUT_F);

    // K4: g = relu(bufB) @ W2 -> bufA[N,128]   ((A@h1)@W2 == A@(h1@W2))
    gemm_f32<true, false, false><<<dim3(mTiles, OUT_F / BN), blk, 0, stream>>>(
        bufB, W2, nullptr, bufA, N, HID_F, OUT_F, OUT_F, 0);

    // SpMM2: out[dst, 384:512] += w * g[src]   (F=128 -> 32 lanes/edge)
    {
        long long tot = (long long)E * (OUT_F / 4);
        spmm_atomic<5><<<(int)((tot + 255) / 256), blk, 0, stream>>>(
            bufA, esrc, edst, ew, out, E, OUT_F, LD, OUT_F + HID_F);
    }
}

// Round 2
// 799.038 us; speedup vs baseline: 5.5415x; 5.5415x over previous
//
#include <hip/hip_runtime.h>

#define BM 64
#define BN 64
#define BK 16

// ---------------- fp32 tiled GEMM: C[m, coff+n] = op(A) @ B (+bias) (relu) ----
// A: [M,K] rows at stride lda. B: [K,Nn] row-major. C row stride ldc.
template<bool RELU_IN, bool BIAS, bool RELU_OUT>
__global__ __launch_bounds__(256)
void gemm_f32(const float* __restrict__ A, const float* __restrict__ B,
              const float* __restrict__ bias, float* __restrict__ C,
              int M, int K, int Nn, int lda, int ldc, int coff)
{
    __shared__ float As[BK][BM + 4];
    __shared__ float Bs[BK][BN];

    const int tid = threadIdx.x;       // 256 threads
    const int tx = tid & 15;           // N direction
    const int ty = tid >> 4;           // M direction
    const int mBase = blockIdx.x * BM;
    const int nBase = blockIdx.y * BN;

    float acc[4][4];
#pragma unroll
    for (int i = 0; i < 4; ++i)
#pragma unroll
        for (int j = 0; j < 4; ++j) acc[i][j] = 0.f;

    const int ar = tid >> 2;           // 0..63   (A tile row)
    const int ac = (tid & 3) * 4;      // 0,4,8,12 (A tile col, float4)
    const int br = tid >> 4;           // 0..15   (B tile row)
    const int bc = (tid & 15) * 4;     // 0..60   (B tile col, float4)

    for (int k0 = 0; k0 < K; k0 += BK) {
        float4 a4 = make_float4(0.f, 0.f, 0.f, 0.f);
        const int gm = mBase + ar;
        if (gm < M) a4 = *(const float4*)&A[(long long)gm * lda + k0 + ac];
        if (RELU_IN) {
            a4.x = fmaxf(a4.x, 0.f); a4.y = fmaxf(a4.y, 0.f);
            a4.z = fmaxf(a4.z, 0.f); a4.w = fmaxf(a4.w, 0.f);
        }
        As[ac + 0][ar] = a4.x;
        As[ac + 1][ar] = a4.y;
        As[ac + 2][ar] = a4.z;
        As[ac + 3][ar] = a4.w;

        float4 b4 = *(const float4*)&B[(long long)(k0 + br) * Nn + nBase + bc];
        *(float4*)&Bs[br][bc] = b4;

        __syncthreads();
#pragma unroll
        for (int k = 0; k < BK; ++k) {
            float4 av = *(const float4*)&As[k][ty * 4];
            float4 bv = *(const float4*)&Bs[k][tx * 4];
            float a[4] = {av.x, av.y, av.z, av.w};
            float b[4] = {bv.x, bv.y, bv.z, bv.w};
#pragma unroll
            for (int i = 0; i < 4; ++i)
#pragma unroll
                for (int j = 0; j < 4; ++j)
                    acc[i][j] = fmaf(a[i], b[j], acc[i][j]);
        }
        __syncthreads();
    }

#pragma unroll
    for (int i = 0; i < 4; ++i) {
        const int gm = mBase + ty * 4 + i;
        if (gm >= M) continue;
        float4 o;
        float* op = &o.x;
#pragma unroll
        for (int j = 0; j < 4; ++j) {
            float v = acc[i][j];
            if (BIAS) v += bias[nBase + tx * 4 + j];
            if (RELU_OUT) v = fmaxf(v, 0.f);
            op[j] = v;
        }
        *(float4*)&C[(long long)gm * ldc + coff + nBase + tx * 4] = o;
    }
}

// ---------------- CSR build: counting sort by dst -----------------------------
__global__ __launch_bounds__(256)
void zero_int(int* __restrict__ p, int n)
{
    int i = blockIdx.x * blockDim.x + threadIdx.x;
    if (i < n) p[i] = 0;
}

__global__ __launch_bounds__(256)
void hist_kernel(const int* __restrict__ dst, int* __restrict__ cnt, int E)
{
    int e = blockIdx.x * blockDim.x + threadIdx.x;
    if (e < E) atomicAdd(&cnt[dst[e]], 1);
}

// single workgroup: exclusive scan of cnt[0..n) (aliased with rowptr),
// writes rowptr[0..n], and pos[i] = rowptr[i] for the scatter pass.
__global__ __launch_bounds__(256)
void scan_kernel(int* __restrict__ rowptr, int* __restrict__ pos, int n)
{
    __shared__ int sums[256];
    const int tid = threadIdx.x;
    const int chunk = (n + 255) / 256;
    const int start = tid * chunk;
    const int end = min(start + chunk, n);

    int s = 0;
    for (int i = start; i < end; ++i) s += rowptr[i];
    sums[tid] = s;
    __syncthreads();
    // Hillis-Steele inclusive scan over 256 partial sums
    for (int off = 1; off < 256; off <<= 1) {
        int v = (tid >= off) ? sums[tid - off] : 0;
        __syncthreads();
        sums[tid] += v;
        __syncthreads();
    }
    int run = (tid > 0) ? sums[tid - 1] : 0;   // exclusive base
    for (int i = start; i < end; ++i) {
        int c = rowptr[i];          // read before overwrite (aliased)
        rowptr[i] = run;
        pos[i] = run;
        run += c;
    }
    if (tid == 0) rowptr[n] = sums[255];
}

__global__ __launch_bounds__(256)
void scatter_kernel(const int* __restrict__ src, const int* __restrict__ dst,
                    const float* __restrict__ w, int* __restrict__ pos,
                    int2* __restrict__ packed, int E)
{
    int e = blockIdx.x * blockDim.x + threadIdx.x;
    if (e >= E) return;
    int p = atomicAdd(&pos[dst[e]], 1);
    packed[p] = make_int2(src[e], __float_as_int(w[e]));
}

// ---------------- gather SpMM: out[r, coff+:F] = (relu)(sum w * x[src, :F]) ---
// TPR lanes per row, each lane owns one float4 (TPR = F/4).
template<int TPR, bool RELU>
__global__ __launch_bounds__(256)
void spmm_csr(const float* __restrict__ x, const int* __restrict__ rowptr,
              const int2* __restrict__ packed, float* __restrict__ out,
              int N, int F, int ldo, int coff)
{
    const int rpb = 256 / TPR;
    const int r = blockIdx.x * rpb + threadIdx.x / TPR;
    const int lane = threadIdx.x % TPR;
    if (r >= N) return;
    const int beg = rowptr[r];
    const int end = rowptr[r + 1];
    const int col = lane * 4;
    float4 acc = make_float4(0.f, 0.f, 0.f, 0.f);
    for (int i = beg; i < end; ++i) {
        int2 e = packed[i];
        float wt = __int_as_float(e.y);
        float4 v = *(const float4*)&x[(long long)e.x * F + col];
        acc.x = fmaf(wt, v.x, acc.x);
        acc.y = fmaf(wt, v.y, acc.y);
        acc.z = fmaf(wt, v.z, acc.z);
        acc.w = fmaf(wt, v.w, acc.w);
    }
    if (RELU) {
        acc.x = fmaxf(acc.x, 0.f); acc.y = fmaxf(acc.y, 0.f);
        acc.z = fmaxf(acc.z, 0.f); acc.w = fmaxf(acc.w, 0.f);
    }
    *(float4*)&out[(long long)r * ldo + coff + col] = acc;
}

// ---------------- launch ------------------------------------------------------
extern "C" void kernel_launch(void* const* d_in, const int* in_sizes, int n_in,
                              void* d_out, int out_size, void* d_ws, size_t ws_size,
                              hipStream_t stream)
{
    const float* X    = (const float*)d_in[0];
    const int*   esrc = (const int*)  d_in[1];
    const int*   edst = (const int*)  d_in[2];
    const float* ew   = (const float*)d_in[3];
    const float* W1   = (const float*)d_in[4];
    const float* W2   = (const float*)d_in[5];
    const float* mw1  = (const float*)d_in[6];
    const float* mb1  = (const float*)d_in[7];
    const float* mw2  = (const float*)d_in[8];
    const float* mb2  = (const float*)d_in[9];

    const int IN_F = 256, HID_F = 256, OUT_F = 128;
    const int N  = in_sizes[0] / IN_F;
    const int E  = in_sizes[1];
    const int LD = OUT_F + HID_F + OUT_F;   // 512

    float* out  = (float*)d_out;
    float* bufA = (float*)d_ws;                       // Y1 [N,256]
    float* bufB = bufA + (size_t)N * HID_F;           // S1 [N,256], later g [N,128]
    int*   rowptr = (int*)(bufB + (size_t)N * HID_F); // N+1 (padded to even)
    int*   pos    = rowptr + (((N + 1) + 1) & ~1);    // N
    int2*  packed = (int2*)(pos + ((N + 1) & ~1));    // E

    dim3 blk(256);
    const int mTiles = (N + BM - 1) / BM;

    // ---- CSR build (independent of GEMMs) ----
    zero_int<<<(N + 1 + 255) / 256, blk, 0, stream>>>(rowptr, N + 1);
    hist_kernel<<<(E + 255) / 256, blk, 0, stream>>>(edst, rowptr, E);
    scan_kernel<<<1, blk, 0, stream>>>(rowptr, pos, N);
    scatter_kernel<<<(E + 255) / 256, blk, 0, stream>>>(esrc, edst, ew, pos, packed, E);

    // K1: S1 = relu(X @ mlp_w1 + b1)  -> bufB
    gemm_f32<false, true, true><<<dim3(mTiles, HID_F / BN), blk, 0, stream>>>(
        X, mw1, mb1, bufB, N, IN_F, HID_F, IN_F, HID_F, 0);

    // K2: self_out = S1 @ mlp_w2 + b2 -> out[:, 0:128]
    gemm_f32<false, true, false><<<dim3(mTiles, OUT_F / BN), blk, 0, stream>>>(
        bufB, mw2, mb2, out, N, HID_F, OUT_F, HID_F, LD, 0);

    // K3: Y1 = X @ W1 -> bufA   (A@(X@W1) == (A@X)@W1)
    gemm_f32<false, false, false><<<dim3(mTiles, HID_F / BN), blk, 0, stream>>>(
        X, W1, nullptr, bufA, N, IN_F, HID_F, IN_F, HID_F, 0);

    // SpMM1 (gather): h1 = relu(sum w*Y1[src]) -> out[:, 128:384]
    spmm_csr<64, true><<<(N + 3) / 4, blk, 0, stream>>>(
        bufA, rowptr, packed, out, N, HID_F, LD, OUT_F);

    // K4: g = h1 @ W2 -> bufB[N,128]  (reads h1 from out slice, lda=512)
    gemm_f32<false, false, false><<<dim3(mTiles, OUT_F / BN), blk, 0, stream>>>(
        out + OUT_F, W2, nullptr, bufB, N, HID_F, OUT_F, LD, OUT_F, 0);

    // SpMM2 (gather): out[:, 384:512] = sum w * g[src]
    spmm_csr<32, false><<<(N + 7) / 8, blk, 0, stream>>>(
        bufB, rowptr, packed, out, N, OUT_F, LD, OUT_F + HID_F);
}

// Round 3
// 459.817 us; speedup vs baseline: 9.6297x; 1.7377x over previous
//
#include <hip/hip_runtime.h>

typedef short  bf16x8 __attribute__((ext_vector_type(8)));
typedef float  f32x4  __attribute__((ext_vector_type(4)));

__device__ __forceinline__ unsigned short f2bf(float x) {
    unsigned int u = __float_as_uint(x);
    u += 0x7FFFu + ((u >> 16) & 1u);   // round-to-nearest-even
    return (unsigned short)(u >> 16);
}
__device__ __forceinline__ unsigned int pack2(float lo, float hi) {
    return (unsigned int)f2bf(lo) | ((unsigned int)f2bf(hi) << 16);
}

// ---------------- bf16 MFMA GEMM ---------------------------------------------
// A: bf16 [Mp][256] row-major. Bt: bf16 [Nn][256] (B transposed). K=256 fixed.
// OUT_BF16: C -> bf16 [Mp][Nn] (all rows). else: C -> f32 [gm*ldc + coff + n], gm<M.
template<bool BIAS, bool RELU, bool OUT_BF16>
__global__ __launch_bounds__(256)
void gemm_mfma(const unsigned short* __restrict__ A,
               const unsigned short* __restrict__ Bt,
               const float* __restrict__ bias, void* __restrict__ Cout,
               int M, int Nn, int ldc, int coff)
{
    constexpr int K = 256, BK = 32, ROWP = 40;   // 40 shorts = 80 B row stride (2-way banks only)
    __shared__ unsigned short As[128 * ROWP];
    __shared__ unsigned short Bs[64 * ROWP];

    const int tid = threadIdx.x;
    const int lane = tid & 63, wid = tid >> 6;
    const int wm = wid & 1, wn = wid >> 1;       // 2x2 wave grid: 64 rows x 32 cols each
    const int l15 = lane & 15, lq = lane >> 4;
    const int mBase = blockIdx.x * 128, nBase = blockIdx.y * 64;

    f32x4 acc[4][2];
#pragma unroll
    for (int mt = 0; mt < 4; ++mt)
#pragma unroll
        for (int nt = 0; nt < 2; ++nt)
            acc[mt][nt] = (f32x4){0.f, 0.f, 0.f, 0.f};

    const int sr = tid >> 2;            // staging row 0..63
    const int sc = (tid & 3) * 8;       // staging col (ushorts)

    for (int k0 = 0; k0 < K; k0 += BK) {
        *(uint4*)&As[sr * ROWP + sc] =
            *(const uint4*)&A[(size_t)(mBase + sr) * K + k0 + sc];
        *(uint4*)&As[(sr + 64) * ROWP + sc] =
            *(const uint4*)&A[(size_t)(mBase + sr + 64) * K + k0 + sc];
        *(uint4*)&Bs[sr * ROWP + sc] =
            *(const uint4*)&Bt[(size_t)(nBase + sr) * K + k0 + sc];
        __syncthreads();

        bf16x8 af[4], bfr[2];
#pragma unroll
        for (int mt = 0; mt < 4; ++mt)
            af[mt] = *(const bf16x8*)&As[(wm * 64 + mt * 16 + l15) * ROWP + lq * 8];
#pragma unroll
        for (int nt = 0; nt < 2; ++nt)
            bfr[nt] = *(const bf16x8*)&Bs[(wn * 32 + nt * 16 + l15) * ROWP + lq * 8];
#pragma unroll
        for (int mt = 0; mt < 4; ++mt)
#pragma unroll
            for (int nt = 0; nt < 2; ++nt)
                acc[mt][nt] = __builtin_amdgcn_mfma_f32_16x16x32_bf16(
                    af[mt], bfr[nt], acc[mt][nt], 0, 0, 0);
        __syncthreads();
    }

#pragma unroll
    for (int mt = 0; mt < 4; ++mt) {
#pragma unroll
        for (int nt = 0; nt < 2; ++nt) {
            const int gn = nBase + wn * 32 + nt * 16 + l15;
            const float bv = BIAS ? bias[gn] : 0.f;
#pragma unroll
            for (int i = 0; i < 4; ++i) {
                const int gm = mBase + wm * 64 + mt * 16 + lq * 4 + i;
                float v = acc[mt][nt][i] + bv;
                if (RELU) v = fmaxf(v, 0.f);
                if (OUT_BF16) {
                    ((unsigned short*)Cout)[(size_t)gm * Nn + gn] = f2bf(v);
                } else {
                    if (gm < M)
                        ((float*)Cout)[(size_t)gm * ldc + coff + gn] = v;
                }
            }
        }
    }
}

// ---------------- conversion kernels -----------------------------------------
__global__ __launch_bounds__(256)
void convert_x(const float* __restrict__ X, unsigned short* __restrict__ Xb,
               int N, int Mp)
{
    int i = blockIdx.x * 256 + threadIdx.x;
    if (i >= Mp * 32) return;               // 8 elems per thread, 256 cols
    size_t base = (size_t)i * 8;
    int row = (int)(base >> 8);
    uint4 o;
    if (row < N) {
        const float4 a = *(const float4*)&X[base];
        const float4 b = *(const float4*)&X[base + 4];
        o.x = pack2(a.x, a.y); o.y = pack2(a.z, a.w);
        o.z = pack2(b.x, b.y); o.w = pack2(b.z, b.w);
    } else {
        o = make_uint4(0, 0, 0, 0);
    }
    *(uint4*)&Xb[base] = o;
}

// W [256][Nn] row-major fp32 -> Wt [Nn][256] bf16
__global__ __launch_bounds__(256)
void convert_wt(const float* __restrict__ W, unsigned short* __restrict__ Wt, int Nn)
{
    int i = blockIdx.x * 256 + threadIdx.x;
    if (i >= Nn * 256) return;
    int n = i >> 8, k = i & 255;
    Wt[i] = f2bf(W[k * Nn + n]);
}

// ---------------- CSR build ---------------------------------------------------
__global__ __launch_bounds__(256)
void zero_int(int* __restrict__ p, int n)
{
    int i = blockIdx.x * 256 + threadIdx.x;
    if (i < n) p[i] = 0;
}

__global__ __launch_bounds__(256)
void hist_kernel(const int* __restrict__ dst, int* __restrict__ cnt, int E)
{
    int e = blockIdx.x * 256 + threadIdx.x;
    if (e < E) atomicAdd(&cnt[dst[e]], 1);
}

__global__ __launch_bounds__(256)
void reduce_chunks(const int* __restrict__ cnt, int* __restrict__ bsum, int n)
{
    __shared__ int s[256];
    int i = blockIdx.x * 256 + threadIdx.x;
    s[threadIdx.x] = (i < n) ? cnt[i] : 0;
    __syncthreads();
    for (int o = 128; o > 0; o >>= 1) {
        if (threadIdx.x < o) s[threadIdx.x] += s[threadIdx.x + o];
        __syncthreads();
    }
    if (threadIdx.x == 0) bsum[blockIdx.x] = s[0];
}

__global__ __launch_bounds__(256)
void scan_bsum(int* __restrict__ bsum, int nb, int* __restrict__ rowptr, int n)
{
    __shared__ int s[256];
    int t = threadIdx.x;
    int v = (t < nb) ? bsum[t] : 0;
    s[t] = v;
    __syncthreads();
    for (int o = 1; o < 256; o <<= 1) {
        int u = (t >= o) ? s[t - o] : 0;
        __syncthreads();
        s[t] += u;
        __syncthreads();
    }
    if (t < nb) bsum[t] = s[t] - v;        // exclusive block base
    if (t == 255) rowptr[n] = s[255];      // total = E
}

// cnt may alias rowptr (each i is read once then written once by the same thread)
__global__ __launch_bounds__(256)
void scan_write(const int* cnt, const int* __restrict__ bsum,
                int* rowptr, int* __restrict__ pos, int n)
{
    __shared__ int s[256];
    int t = threadIdx.x;
    int i = blockIdx.x * 256 + t;
    int v = (i < n) ? cnt[i] : 0;
    s[t] = v;
    __syncthreads();
    for (int o = 1; o < 256; o <<= 1) {
        int u = (t >= o) ? s[t - o] : 0;
        __syncthreads();
        s[t] += u;
        __syncthreads();
    }
    if (i < n) {
        int ex = bsum[blockIdx.x] + s[t] - v;
        rowptr[i] = ex;
        pos[i] = ex;
    }
}

__global__ __launch_bounds__(256)
void scatter_kernel(const int* __restrict__ src, const int* __restrict__ dst,
                    const float* __restrict__ w, int* __restrict__ pos,
                    int2* __restrict__ packed, int E)
{
    int e = blockIdx.x * 256 + threadIdx.x;
    if (e >= E) return;
    int p = atomicAdd(&pos[dst[e]], 1);
    packed[p] = make_int2(src[e], __float_as_int(w[e]));
}

// ---------------- gather SpMM over bf16 features ------------------------------
// x: bf16 [*, F]; TPR lanes/row, 8 features per lane. Writes fp32 slice, and
// optionally a bf16 copy (for the next GEMM's A operand).
template<int TPR, bool RELU, bool DUAL>
__global__ __launch_bounds__(256)
void spmm_csr_bf16(const unsigned short* __restrict__ x,
                   const int* __restrict__ rowptr, const int2* __restrict__ packed,
                   float* __restrict__ outf, unsigned short* __restrict__ outb,
                   int N, int F, int ldo, int coff)
{
    const int rpb = 256 / TPR;
    const int r = blockIdx.x * rpb + threadIdx.x / TPR;
    const int lane = threadIdx.x % TPR;
    if (r >= N) return;
    const int beg = rowptr[r], end = rowptr[r + 1];
    const int col = lane * 8;
    float acc[8] = {0.f, 0.f, 0.f, 0.f, 0.f, 0.f, 0.f, 0.f};
    for (int i = beg; i < end; ++i) {
        int2 e = packed[i];
        float wt = __int_as_float(e.y);
        uint4 v = *(const uint4*)&x[(size_t)e.x * F + col];
        unsigned int vs[4] = {v.x, v.y, v.z, v.w};
#pragma unroll
        for (int j = 0; j < 4; ++j) {
            float lo = __uint_as_float(vs[j] << 16);
            float hi = __uint_as_float(vs[j] & 0xFFFF0000u);
            acc[2 * j]     = fmaf(wt, lo, acc[2 * j]);
            acc[2 * j + 1] = fmaf(wt, hi, acc[2 * j + 1]);
        }
    }
    if (RELU) {
#pragma unroll
        for (int j = 0; j < 8; ++j) acc[j] = fmaxf(acc[j], 0.f);
    }
    float* o = &outf[(size_t)r * ldo + coff + col];
    *(float4*)o       = make_float4(acc[0], acc[1], acc[2], acc[3]);
    *(float4*)(o + 4) = make_float4(acc[4], acc[5], acc[6], acc[7]);
    if (DUAL) {
        uint4 p;
        p.x = pack2(acc[0], acc[1]); p.y = pack2(acc[2], acc[3]);
        p.z = pack2(acc[4], acc[5]); p.w = pack2(acc[6], acc[7]);
        *(uint4*)&outb[(size_t)r * F + col] = p;
    }
}

// ---------------- launch ------------------------------------------------------
extern "C" void kernel_launch(void* const* d_in, const int* in_sizes, int n_in,
                              void* d_out, int out_size, void* d_ws, size_t ws_size,
                              hipStream_t stream)
{
    const float* X    = (const float*)d_in[0];
    const int*   esrc = (const int*)  d_in[1];
    const int*   edst = (const int*)  d_in[2];
    const float* ew   = (const float*)d_in[3];
    const float* W1   = (const float*)d_in[4];
    const float* W2   = (const float*)d_in[5];
    const float* mw1  = (const float*)d_in[6];
    const float* mb1  = (const float*)d_in[7];
    const float* mw2  = (const float*)d_in[8];
    const float* mb2  = (const float*)d_in[9];

    const int IN_F = 256, HID_F = 256, OUT_F = 128;
    const int N  = in_sizes[0] / IN_F;
    const int E  = in_sizes[1];
    const int LD = OUT_F + HID_F + OUT_F;       // 512
    const int Mp = (N + 127) & ~127;            // 128-aligned row count

    float* out = (float*)d_out;

    // workspace layout (bf16 = ushort)
    unsigned short* Xb   = (unsigned short*)d_ws;           // [Mp][256]
    unsigned short* buf1 = Xb   + (size_t)Mp * 256;         // S1b, then h1b [Mp][256]
    unsigned short* buf2 = buf1 + (size_t)Mp * 256;         // Y1b [Mp][256], then gb [Mp][128]
    unsigned short* mw1t = buf2 + (size_t)Mp * 256;         // [256][256]
    unsigned short* mw2t = mw1t + 256 * 256;                // [128][256]
    unsigned short* w1t  = mw2t + 128 * 256;                // [256][256]
    unsigned short* w2t  = w1t  + 256 * 256;                // [128][256]
    int* rowptr = (int*)(w2t + 128 * 256);                  // N+1 (pad to mult 4)
    int* bsum   = rowptr + (((N + 1) + 3) & ~3);            // 256
    int* pos    = bsum + 256;                               // N
    int2* packed = (int2*)(pos + ((N + 1) & ~1));           // E (8B aligned)

    dim3 blk(256);
    const int nb = (N + 255) / 256;
    const int mT = Mp / 128;

    // ---- CSR build ----
    zero_int<<<(N + 1 + 255) / 256, blk, 0, stream>>>(rowptr, N + 1);
    hist_kernel<<<(E + 255) / 256, blk, 0, stream>>>(edst, rowptr, E);
    reduce_chunks<<<nb, blk, 0, stream>>>(rowptr, bsum, N);
    scan_bsum<<<1, blk, 0, stream>>>(bsum, nb, rowptr, N);
    scan_write<<<nb, blk, 0, stream>>>(rowptr, bsum, rowptr, pos, N);
    scatter_kernel<<<(E + 255) / 256, blk, 0, stream>>>(esrc, edst, ew, pos, packed, E);

    // ---- bf16 conversions ----
    convert_x<<<(Mp * 32 + 255) / 256, blk, 0, stream>>>(X, Xb, N, Mp);
    convert_wt<<<(256 * 256) / 256, blk, 0, stream>>>(mw1, mw1t, 256);
    convert_wt<<<(128 * 256) / 256, blk, 0, stream>>>(mw2, mw2t, 128);
    convert_wt<<<(256 * 256) / 256, blk, 0, stream>>>(W1, w1t, 256);
    convert_wt<<<(128 * 256) / 256, blk, 0, stream>>>(W2, w2t, 128);

    // K1: S1b = relu(Xb @ mw1 + b1) -> buf1 (bf16)
    gemm_mfma<true, true, true><<<dim3(mT, 4), blk, 0, stream>>>(
        Xb, mw1t, mb1, buf1, N, HID_F, 0, 0);

    // K2: out[:,0:128] = S1b @ mw2 + b2 (fp32)
    gemm_mfma<true, false, false><<<dim3(mT, 2), blk, 0, stream>>>(
        buf1, mw2t, mb2, out, N, OUT_F, LD, 0);

    // K3: Y1b = Xb @ W1 -> buf2 (bf16)
    gemm_mfma<false, false, true><<<dim3(mT, 4), blk, 0, stream>>>(
        Xb, w1t, nullptr, buf2, N, HID_F, 0, 0);

    // SpMM1: h1 = relu(A @ Y1) -> out[:,128:384] fp32  +  buf1 bf16 (h1b)
    spmm_csr_bf16<32, true, true><<<(N + 7) / 8, blk, 0, stream>>>(
        buf2, rowptr, packed, out, buf1, N, HID_F, LD, OUT_F);

    // K4: gb = h1b @ W2 -> buf2 (bf16, [Mp][128])
    gemm_mfma<false, false, true><<<dim3(mT, 2), blk, 0, stream>>>(
        buf1, w2t, nullptr, buf2, N, OUT_F, 0, 0);

    // SpMM2: out[:,384:512] = A @ g (fp32)
    spmm_csr_bf16<16, false, false><<<(N + 15) / 16, blk, 0, stream>>>(
        buf2, rowptr, packed, out, nullptr, N, OUT_F, LD, OUT_F + HID_F);
}

// Round 4
// 411.960 us; speedup vs baseline: 10.7483x; 1.1162x over previous
//
#include <hip/hip_runtime.h>

typedef short  bf16x8 __attribute__((ext_vector_type(8)));
typedef float  f32x4  __attribute__((ext_vector_type(4)));

__device__ __forceinline__ unsigned short f2bf(float x) {
    unsigned int u = __float_as_uint(x);
    u += 0x7FFFu + ((u >> 16) & 1u);   // round-to-nearest-even
    return (unsigned short)(u >> 16);
}
__device__ __forceinline__ unsigned int pack2(float lo, float hi) {
    return (unsigned int)f2bf(lo) | ((unsigned int)f2bf(hi) << 16);
}

// ---------------- bf16 MFMA GEMM, 128x128 tile, K=256 -------------------------
// A: fp32 (A_F32, guarded to M rows, lda floats) or bf16 (padded ws, lda shorts).
// Bt: bf16 [Nn][256] (B transposed). C: bf16 arena (ldc) or fp32 (guarded, ldc).
// EPI: 0=none, 2=+bias, 3=relu(+bias) for gn<256 only (fused MLP1+conv1 weights).
template<bool A_F32, bool OUT_BF16, int EPI>
__global__ __launch_bounds__(256)
void gemm_mfma(const void* __restrict__ Av, const unsigned short* __restrict__ Bt,
               const float* __restrict__ bias, void* __restrict__ Cout,
               int M, int Nn, int lda, int ldc, int coff)
{
    constexpr int K = 256, BK = 32, ROWP = 40;  // 80B LDS row stride (conflict-free, measured R3)
    __shared__ unsigned short As[128 * ROWP];
    __shared__ unsigned short Bs[128 * ROWP];

    const int tid = threadIdx.x;
    const int lane = tid & 63, wid = tid >> 6;
    const int wm = wid & 1, wn = wid >> 1;      // 2x2 waves, each 64x64
    const int l15 = lane & 15, lq = lane >> 4;
    const int mBase = blockIdx.x * 128, nBase = blockIdx.y * 128;

    f32x4 acc[4][4];
#pragma unroll
    for (int mt = 0; mt < 4; ++mt)
#pragma unroll
        for (int nt = 0; nt < 4; ++nt)
            acc[mt][nt] = (f32x4){0.f, 0.f, 0.f, 0.f};

    const int srow = tid >> 1;          // 0..127
    const int sseg = (tid & 1) * 16;    // 0 / 16 shorts

    for (int k0 = 0; k0 < K; k0 += BK) {
        if (A_F32) {
            const float* Af = (const float*)Av;
            const int gm = mBase + srow;
            float4 f0, f1, f2, f3;
            if (gm < M) {
                const float4* p = (const float4*)&Af[(size_t)gm * lda + k0 + sseg];
                f0 = p[0]; f1 = p[1]; f2 = p[2]; f3 = p[3];
            } else {
                f0 = f1 = f2 = f3 = make_float4(0.f, 0.f, 0.f, 0.f);
            }
            uint4 o0, o1;
            o0.x = pack2(f0.x, f0.y); o0.y = pack2(f0.z, f0.w);
            o0.z = pack2(f1.x, f1.y); o0.w = pack2(f1.z, f1.w);
            o1.x = pack2(f2.x, f2.y); o1.y = pack2(f2.z, f2.w);
            o1.z = pack2(f3.x, f3.y); o1.w = pack2(f3.z, f3.w);
            *(uint4*)&As[srow * ROWP + sseg]     = o0;
            *(uint4*)&As[srow * ROWP + sseg + 8] = o1;
        } else {
            const unsigned short* Ab = (const unsigned short*)Av;
            const uint4* p = (const uint4*)&Ab[(size_t)(mBase + srow) * lda + k0 + sseg];
            *(uint4*)&As[srow * ROWP + sseg]     = p[0];
            *(uint4*)&As[srow * ROWP + sseg + 8] = p[1];
        }
        {
            const uint4* q = (const uint4*)&Bt[(size_t)(nBase + srow) * 256 + k0 + sseg];
            *(uint4*)&Bs[srow * ROWP + sseg]     = q[0];
            *(uint4*)&Bs[srow * ROWP + sseg + 8] = q[1];
        }
        __syncthreads();

        bf16x8 af[4], bfr[4];
#pragma unroll
        for (int mt = 0; mt < 4; ++mt)
            af[mt] = *(const bf16x8*)&As[(wm * 64 + mt * 16 + l15) * ROWP + lq * 8];
#pragma unroll
        for (int nt = 0; nt < 4; ++nt)
            bfr[nt] = *(const bf16x8*)&Bs[(wn * 64 + nt * 16 + l15) * ROWP + lq * 8];
#pragma unroll
        for (int mt = 0; mt < 4; ++mt)
#pragma unroll
            for (int nt = 0; nt < 4; ++nt)
                acc[mt][nt] = __builtin_amdgcn_mfma_f32_16x16x32_bf16(
                    af[mt], bfr[nt], acc[mt][nt], 0, 0, 0);
        __syncthreads();
    }

#pragma unroll
    for (int mt = 0; mt < 4; ++mt) {
#pragma unroll
        for (int nt = 0; nt < 4; ++nt) {
            const int gn = nBase + wn * 64 + nt * 16 + l15;
#pragma unroll
            for (int i = 0; i < 4; ++i) {
                const int gm = mBase + wm * 64 + mt * 16 + lq * 4 + i;
                float v = acc[mt][nt][i];
                if (EPI == 2) v += bias[gn];
                if (EPI == 3) { if (gn < 256) v = fmaxf(v + bias[gn], 0.f); }
                if (OUT_BF16) {
                    ((unsigned short*)Cout)[(size_t)gm * ldc + coff + gn] = f2bf(v);
                } else {
                    if (gm < M)
                        ((float*)Cout)[(size_t)gm * ldc + coff + gn] = v;
                }
            }
        }
    }
}

// ---------------- setup: weight transpose-convert + rowptr zero ---------------
// warena rows: [0,256)=mw1^T, [256,512)=W1^T, [512,640)=mw2^T, [640,768)=W2^T
__global__ __launch_bounds__(256)
void setup_kernel(const float* __restrict__ mw1, const float* __restrict__ W1,
                  const float* __restrict__ mw2, const float* __restrict__ W2,
                  unsigned short* __restrict__ warena, int* __restrict__ rowptr, int n1)
{
    int i = blockIdx.x * 256 + threadIdx.x;
    if (i < n1) rowptr[i] = 0;
    if (i >= 768 * 256) return;
    int r = i >> 8, k = i & 255;
    float v;
    if (r < 256)      v = mw1[k * 256 + r];
    else if (r < 512) v = W1[k * 256 + (r - 256)];
    else if (r < 640) v = mw2[k * 128 + (r - 512)];
    else              v = W2[k * 128 + (r - 640)];
    warena[i] = f2bf(v);
}

// ---------------- CSR build ---------------------------------------------------
__global__ __launch_bounds__(256)
void hist_kernel(const int* __restrict__ dst, int* __restrict__ cnt, int E)
{
    int e = blockIdx.x * 256 + threadIdx.x;
    if (e < E) atomicAdd(&cnt[dst[e]], 1);
}

__global__ __launch_bounds__(256)
void reduce_chunks(const int* __restrict__ cnt, int* __restrict__ bsum, int n)
{
    __shared__ int s[256];
    int i = blockIdx.x * 256 + threadIdx.x;
    s[threadIdx.x] = (i < n) ? cnt[i] : 0;
    __syncthreads();
    for (int o = 128; o > 0; o >>= 1) {
        if (threadIdx.x < o) s[threadIdx.x] += s[threadIdx.x + o];
        __syncthreads();
    }
    if (threadIdx.x == 0) bsum[blockIdx.x] = s[0];
}

__global__ __launch_bounds__(256)
void scan_bsum(int* __restrict__ bsum, int nb, int* __restrict__ rowptr, int n)
{
    __shared__ int s[256];
    int t = threadIdx.x;
    int v = (t < nb) ? bsum[t] : 0;
    s[t] = v;
    __syncthreads();
    for (int o = 1; o < 256; o <<= 1) {
        int u = (t >= o) ? s[t - o] : 0;
        __syncthreads();
        s[t] += u;
        __syncthreads();
    }
    if (t < nb) bsum[t] = s[t] - v;
    if (t == 255) rowptr[n] = s[255];
}

__global__ __launch_bounds__(256)
void scan_write(const int* cnt, const int* __restrict__ bsum,
                int* rowptr, int* __restrict__ pos, int n)
{
    __shared__ int s[256];
    int t = threadIdx.x;
    int i = blockIdx.x * 256 + t;
    int v = (i < n) ? cnt[i] : 0;
    s[t] = v;
    __syncthreads();
    for (int o = 1; o < 256; o <<= 1) {
        int u = (t >= o) ? s[t - o] : 0;
        __syncthreads();
        s[t] += u;
        __syncthreads();
    }
    if (i < n) {
        int ex = bsum[blockIdx.x] + s[t] - v;
        rowptr[i] = ex;
        pos[i] = ex;
    }
}

__global__ __launch_bounds__(256)
void scatter_kernel(const int* __restrict__ src, const int* __restrict__ dst,
                    const float* __restrict__ w, int* __restrict__ pos,
                    int2* __restrict__ packed, int E)
{
    int e = blockIdx.x * 256 + threadIdx.x;
    if (e >= E) return;
    int p = atomicAdd(&pos[dst[e]], 1);
    packed[p] = make_int2(src[e], __float_as_int(w[e]));
}

// ---------------- gather SpMM over bf16 rows, 2-way edge unroll ---------------
// x row stride ldx shorts; TPR lanes/row, 8 feats/lane. fp32 out slice (ldo,coff);
// optional bf16 copy at stride ldd.
template<int TPR, bool RELU, bool DUAL>
__global__ __launch_bounds__(256)
void spmm_csr_bf16(const unsigned short* __restrict__ x,
                   const int* __restrict__ rowptr, const int2* __restrict__ packed,
                   float* __restrict__ outf, unsigned short* __restrict__ outb,
                   int N, int ldx, int ldo, int coff, int ldd)
{
    const int rpb = 256 / TPR;
    const int r = blockIdx.x * rpb + threadIdx.x / TPR;
    const int lane = threadIdx.x % TPR;
    if (r >= N) return;
    const int beg = rowptr[r], end = rowptr[r + 1];
    const unsigned short* xp = x + lane * 8;
    float a0[8] = {0, 0, 0, 0, 0, 0, 0, 0};
    float a1[8] = {0, 0, 0, 0, 0, 0, 0, 0};
    int i = beg;
    for (; i + 1 < end; i += 2) {
        int2 e0 = packed[i], e1 = packed[i + 1];
        uint4 v0 = *(const uint4*)&xp[(size_t)e0.x * ldx];
        uint4 v1 = *(const uint4*)&xp[(size_t)e1.x * ldx];
        float w0 = __int_as_float(e0.y), w1 = __int_as_float(e1.y);
        unsigned int s0[4] = {v0.x, v0.y, v0.z, v0.w};
        unsigned int s1[4] = {v1.x, v1.y, v1.z, v1.w};
#pragma unroll
        for (int j = 0; j < 4; ++j) {
            a0[2 * j]     = fmaf(w0, __uint_as_float(s0[j] << 16),        a0[2 * j]);
            a0[2 * j + 1] = fmaf(w0, __uint_as_float(s0[j] & 0xFFFF0000u), a0[2 * j + 1]);
            a1[2 * j]     = fmaf(w1, __uint_as_float(s1[j] << 16),        a1[2 * j]);
            a1[2 * j + 1] = fmaf(w1, __uint_as_float(s1[j] & 0xFFFF0000u), a1[2 * j + 1]);
        }
    }
    if (i < end) {
        int2 e0 = packed[i];
        uint4 v0 = *(const uint4*)&xp[(size_t)e0.x * ldx];
        float w0 = __int_as_float(e0.y);
        unsigned int s0[4] = {v0.x, v0.y, v0.z, v0.w};
#pragma unroll
        for (int j = 0; j < 4; ++j) {
            a0[2 * j]     = fmaf(w0, __uint_as_float(s0[j] << 16),        a0[2 * j]);
            a0[2 * j + 1] = fmaf(w0, __uint_as_float(s0[j] & 0xFFFF0000u), a0[2 * j + 1]);
        }
    }
    float acc[8];
#pragma unroll
    for (int j = 0; j < 8; ++j) {
        acc[j] = a0[j] + a1[j];
        if (RELU) acc[j] = fmaxf(acc[j], 0.f);
    }
    float* o = &outf[(size_t)r * ldo + coff + lane * 8];
    *(float4*)o       = make_float4(acc[0], acc[1], acc[2], acc[3]);
    *(float4*)(o + 4) = make_float4(acc[4], acc[5], acc[6], acc[7]);
    if (DUAL) {
        uint4 p;
        p.x = pack2(acc[0], acc[1]); p.y = pack2(acc[2], acc[3]);
        p.z = pack2(acc[4], acc[5]); p.w = pack2(acc[6], acc[7]);
        *(uint4*)&outb[(size_t)r * ldd + lane * 8] = p;
    }
}

// ---------------- launch ------------------------------------------------------
extern "C" void kernel_launch(void* const* d_in, const int* in_sizes, int n_in,
                              void* d_out, int out_size, void* d_ws, size_t ws_size,
                              hipStream_t stream)
{
    const float* X    = (const float*)d_in[0];
    const int*   esrc = (const int*)  d_in[1];
    const int*   edst = (const int*)  d_in[2];
    const float* ew   = (const float*)d_in[3];
    const float* W1   = (const float*)d_in[4];
    const float* W2   = (const float*)d_in[5];
    const float* mw1  = (const float*)d_in[6];
    const float* mb1  = (const float*)d_in[7];
    const float* mw2  = (const float*)d_in[8];
    const float* mb2  = (const float*)d_in[9];

    const int IN_F = 256, HID_F = 256, OUT_F = 128;
    const int N  = in_sizes[0] / IN_F;
    const int E  = in_sizes[1];
    const int LD = OUT_F + HID_F + OUT_F;       // 512
    const int Mp = (N + 127) & ~127;

    float* out = (float*)d_out;

    // workspace (shorts)
    unsigned short* S1Y1  = (unsigned short*)d_ws;          // [Mp][512]: S1 | Y1
    unsigned short* h1b   = S1Y1 + (size_t)Mp * 512;        // [Mp][256]
    unsigned short* gb    = h1b  + (size_t)Mp * 256;        // [Mp][128]
    unsigned short* warena = gb  + (size_t)Mp * 128;        // [768][256]
    unsigned short* Wc   = warena;                          // [512][256]
    unsigned short* mw2t = warena + 512 * 256;              // [128][256]
    unsigned short* w2t  = warena + 640 * 256;              // [128][256]
    int* rowptr = (int*)(warena + 768 * 256);               // N+1
    int* bsum   = rowptr + (((N + 1) + 3) & ~3);            // 256
    int* pos    = bsum + 256;                               // N
    int2* packed = (int2*)(pos + ((N + 1) & ~1));           // E

    dim3 blk(256);
    const int nb = (N + 255) / 256;
    const int mT = Mp / 128;

    // setup: weight conversion + rowptr zeroing (one kernel)
    setup_kernel<<<768, blk, 0, stream>>>(mw1, W1, mw2, W2, warena, rowptr, N + 1);

    // CSR build
    hist_kernel<<<(E + 255) / 256, blk, 0, stream>>>(edst, rowptr, E);
    reduce_chunks<<<nb, blk, 0, stream>>>(rowptr, bsum, N);
    scan_bsum<<<1, blk, 0, stream>>>(bsum, nb, rowptr, N);
    scan_write<<<nb, blk, 0, stream>>>(rowptr, bsum, rowptr, pos, N);
    scatter_kernel<<<(E + 255) / 256, blk, 0, stream>>>(esrc, edst, ew, pos, packed, E);

    // gemmA: [S1 | Y1] = X @ [mw1 | W1]  (relu+b1 on first 256 cols) -> bf16
    gemm_mfma<true, true, 3><<<dim3(mT, 4), blk, 0, stream>>>(
        X, Wc, mb1, S1Y1, N, 512, IN_F, 512, 0);

    // K2: out[:,0:128] = S1 @ mw2 + b2 (fp32)
    gemm_mfma<false, false, 2><<<dim3(mT, 1), blk, 0, stream>>>(
        S1Y1, mw2t, mb2, out, N, OUT_F, 512, LD, 0);

    // SpMM1: h1 = relu(A @ Y1) -> out[:,128:384] fp32 + h1b bf16
    spmm_csr_bf16<32, true, true><<<(N + 7) / 8, blk, 0, stream>>>(
        S1Y1 + 256, rowptr, packed, out, h1b, N, 512, LD, OUT_F, 256);

    // K4: gb = h1 @ W2 (bf16)
    gemm_mfma<false, true, 0><<<dim3(mT, 1), blk, 0, stream>>>(
        h1b, w2t, nullptr, gb, N, OUT_F, 256, 128, 0);

    // SpMM2: out[:,384:512] = A @ g (fp32)
    spmm_csr_bf16<16, false, false><<<(N + 15) / 16, blk, 0, stream>>>(
        gb, rowptr, packed, out, nullptr, N, 128, LD, OUT_F + HID_F, 0);
}